// Round 4
// baseline (628.835 us; speedup 1.0000x reference)
//
#include <hip/hip_runtime.h>
#include <math.h>

typedef _Float16 f16_t;
typedef _Float16 f16x2 __attribute__((ext_vector_type(2)));
typedef _Float16 f16x8 __attribute__((ext_vector_type(8)));
typedef float f32x4 __attribute__((ext_vector_type(4)));

// Problem dims (fixed by setup_inputs)
constexpr int Bn = 128;       // batch
constexpr int Tn = 512;       // time steps
constexpr int Jn = 700;       // input features
constexpr int Jp = 704;       // padded to 64 multiple (11 x 64)
constexpr int Hn = 512;       // hidden
constexpr int On = 20;        // output classes
constexpr int Mn = Bn * Tn;   // 65536 rows

#define LDS_U32(p) ((__attribute__((address_space(3))) uint32_t*)(p))
#define GLB_U32(p) ((const __attribute__((address_space(1))) uint32_t*)(p))

// ---------------------------------------------------------------------------
// Round-10: FULL revert to the round-0 562us GEMM (single-buffer, 2-barrier,
// gload_lds staging, 2 blocks/CU). All three structural experiments
// (scan block-resize r7, dbuf+counted-vmcnt r8, fused fp32 A-staging r9)
// regressed; at K=512-704 (8-11 iters) there is no steady state for
// source-level pipelining, and cross-block TLP already hides the barrier
// drain (m99/m114).
//   C[M x Nout](fp32) = A[M x LDA](f16) * W[NP x LDW](f16)^T
// BK=64 per barrier (two 32-k slices), all staging via global_load_lds,
// XOR bank swizzle (fetch chunk (lane&3)^((lane>>3)&3), frag chunk
// quad^((fr>>1)&3)) -> ds_read_b128 lands 2-way on banks (free, m136).
// 512 thr = 8 waves (2m x 4n) on 128 x (NT*128); wave = 64 x (NT*32).
// __launch_bounds__(512,4): regs <=128 -> 2 blocks/CU = 16 waves/CU.
// SWZ: XCD-pairing 1-D grid map. Linear ids g and g+8 land on the same XCD
// (round-robin %8); map them to the two N-blocks of the same A-stripe
// (y=(g>>4)*8+(g&7), x=(g>>3)&1) so the A-stripe is fetched into one XCD's
// L2 once instead of two.
// Epilogue: fp32 store + fused per-channel BN stats atomics.
// ---------------------------------------------------------------------------
template <int NT, bool SWZ>
__global__ __launch_bounds__(512, 4) void gemm_f16(
    const f16_t* __restrict__ A, const f16_t* __restrict__ W,
    float* __restrict__ C, float* __restrict__ s_out, float* __restrict__ q_out,
    int LDA, int LDW, int pairs, int Nout)
{
    constexpr int JT = 2 * NT;              // 16-col tiles per wave
    __shared__ __align__(16) f16_t sA[2 * 4096];
    __shared__ __align__(16) f16_t sW[2 * NT * 4096];

    int bx, by;
    if (SWZ) {
        const int g = blockIdx.x;
        by = (g >> 4) * 8 + (g & 7);
        bx = (g >> 3) & 1;
    } else {
        bx = blockIdx.x;
        by = blockIdx.y;
    }
    const int tid  = threadIdx.x;
    const int bm   = by * 128;
    const int bn   = bx * (NT * 128);
    const int lane = tid & 63;
    const int wv   = tid >> 6;              // 0..7
    const int wm   = (wv & 1) * 64;
    const int wn   = (wv >> 1) * (NT * 32);
    const int fr   = lane & 15;
    const int quad = lane >> 4;
    const int srow = lane >> 2;                              // DMA row in chunk
    const int scol = (((lane & 3) ^ ((lane >> 3) & 3)) * 8); // swizzled fetch col
    const int ksw  = ((quad ^ ((fr >> 1) & 3)) * 8);         // swizzled frag col

    f32x4 acc[4][JT];
#pragma unroll
    for (int i = 0; i < 4; ++i)
#pragma unroll
        for (int j = 0; j < JT; ++j) acc[i][j] = {0.f, 0.f, 0.f, 0.f};

    for (int p = 0; p < pairs; ++p) {
        // ---- stage A: 2 k-slices x 8 chunks of 16 rows, spread over waves ----
#pragma unroll
        for (int cc = 0; cc < 2; ++cc) {
            const int c  = wv + cc * 8;     // 0..15
            const int s  = c >> 3;
            const int cr = (c & 7) * 16;
            const int kA = p * 64 + s * 32;
            const uint32_t off = __builtin_amdgcn_readfirstlane(s * 8192 + cr * 64);
            const f16_t* gp = A + (size_t)(bm + cr + srow) * LDA + kA + scol;
            __builtin_amdgcn_global_load_lds(GLB_U32(gp), LDS_U32((char*)sA + off), 16, 0, 0);
        }
        // ---- stage W: 2 k-slices x NT tiles x 8 chunks ----
#pragma unroll
        for (int cc = 0; cc < 2 * NT; ++cc) {
            const int c   = wv + cc * 8;
            const int h   = c / (NT * 8);
            const int rem = c % (NT * 8);
            const int nt  = rem >> 3;
            const int cr  = (rem & 7) * 16;
            const int kW  = p * 64 + h * 32;
            const uint32_t off = __builtin_amdgcn_readfirstlane((h * NT + nt) * 8192 + cr * 64);
            const f16_t* gp = W + (size_t)(bn + nt * 128 + cr + srow) * LDW + kW + scol;
            __builtin_amdgcn_global_load_lds(GLB_U32(gp), LDS_U32((char*)sW + off), 16, 0, 0);
        }
        __syncthreads();

        // ---- consume: 2 x (4 x JT) MFMA per wave between barriers ----
#pragma unroll
        for (int h = 0; h < 2; ++h) {
            f16x8 av[4];
#pragma unroll
            for (int i = 0; i < 4; ++i)
                av[i] = *(const f16x8*)&sA[h * 4096 + (wm + i * 16 + fr) * 32 + ksw];
            f16x8 wf[JT];
#pragma unroll
            for (int jt = 0; jt < JT; ++jt) {
                const int n = wn + jt * 16 + fr;
                wf[jt] = *(const f16x8*)&sW[(h * NT + (n >> 7)) * 4096 + (n & 127) * 32 + ksw];
            }
#pragma unroll
            for (int i = 0; i < 4; ++i)
#pragma unroll
                for (int jt = 0; jt < JT; ++jt)
                    acc[i][jt] = __builtin_amdgcn_mfma_f32_16x16x32_f16(av[i], wf[jt], acc[i][jt], 0, 0, 0);
        }
        __syncthreads();
    }

    // ---- epilogue: fp32 store + fused per-channel BN stats ----
#pragma unroll
    for (int jt = 0; jt < JT; ++jt) {
        const int gcol = bn + wn + jt * 16 + fr;
        float s = 0.f, q = 0.f;
        if (gcol < Nout) {
#pragma unroll
            for (int i = 0; i < 4; ++i) {
#pragma unroll
                for (int rg = 0; rg < 4; ++rg) {
                    const float v = acc[i][jt][rg];
                    C[(size_t)(bm + wm + i * 16 + quad * 4 + rg) * Nout + gcol] = v;
                    s += v;
                    q += v * v;
                }
            }
        }
        s += __shfl_xor(s, 16); s += __shfl_xor(s, 32);
        q += __shfl_xor(q, 16); q += __shfl_xor(q, 32);
        if (quad == 0 && gcol < Nout) {
            atomicAdd(&s_out[gcol], s);
            atomicAdd(&q_out[gcol], q);
        }
    }
}

// ---------------------------------------------------------------------------
// Round-10 NEW: narrow-N GEMM for the readout layer. The old path computed a
// 128-col N-tile with only 20 valid columns (84% of MFMA + W-LDS wasted).
// Here: 8 waves split 8x1 over M (wave = 16 rows x 32 cols), W-tile is
// 32 rows (4 KB LDS), 4 MFMA/iter/wave. Same MFMA shape, same K-order,
// same staging swizzle -> bufR bit-identical to the old gemm3.
// ---------------------------------------------------------------------------
__global__ __launch_bounds__(512, 4) void gemm_narrow(
    const f16_t* __restrict__ A, const f16_t* __restrict__ W,
    float* __restrict__ C, float* __restrict__ s_out, float* __restrict__ q_out,
    int LDA, int LDW, int pairs, int Nout)
{
    __shared__ __align__(16) f16_t sA[2 * 4096];   // 2 slices x 128 rows x 32
    __shared__ __align__(16) f16_t sW[2 * 1024];   // 2 slices x  32 rows x 32

    const int tid  = threadIdx.x;
    const int bm   = blockIdx.x * 128;
    const int lane = tid & 63;
    const int wv   = tid >> 6;              // 0..7
    const int wm   = wv * 16;               // 8 waves x 16 rows = 128
    const int fr   = lane & 15;
    const int quad = lane >> 4;
    const int srow = lane >> 2;
    const int scol = (((lane & 3) ^ ((lane >> 3) & 3)) * 8);
    const int ksw  = ((quad ^ ((fr >> 1) & 3)) * 8);

    f32x4 acc[2];
    acc[0] = {0.f, 0.f, 0.f, 0.f};
    acc[1] = {0.f, 0.f, 0.f, 0.f};

    for (int p = 0; p < pairs; ++p) {
        // ---- stage A: identical to wide path ----
#pragma unroll
        for (int cc = 0; cc < 2; ++cc) {
            const int c  = wv + cc * 8;
            const int s  = c >> 3;
            const int cr = (c & 7) * 16;
            const int kA = p * 64 + s * 32;
            const uint32_t off = __builtin_amdgcn_readfirstlane(s * 8192 + cr * 64);
            const f16_t* gp = A + (size_t)(bm + cr + srow) * LDA + kA + scol;
            __builtin_amdgcn_global_load_lds(GLB_U32(gp), LDS_U32((char*)sA + off), 16, 0, 0);
        }
        // ---- stage W: 2 slices x 2 chunks of 16 rows = 4 chunks, waves 0-3 ----
        if (wv < 4) {
            const int s  = wv >> 1;
            const int cr = (wv & 1) * 16;
            const int kW = p * 64 + s * 32;
            const uint32_t off = __builtin_amdgcn_readfirstlane(s * 2048 + cr * 64);
            const f16_t* gp = W + (size_t)(cr + srow) * LDW + kW + scol;
            __builtin_amdgcn_global_load_lds(GLB_U32(gp), LDS_U32((char*)sW + off), 16, 0, 0);
        }
        __syncthreads();

#pragma unroll
        for (int h = 0; h < 2; ++h) {
            const f16x8 av = *(const f16x8*)&sA[h * 4096 + (wm + fr) * 32 + ksw];
#pragma unroll
            for (int jt = 0; jt < 2; ++jt) {
                const f16x8 wf = *(const f16x8*)&sW[h * 1024 + (jt * 16 + fr) * 32 + ksw];
                acc[jt] = __builtin_amdgcn_mfma_f32_16x16x32_f16(av, wf, acc[jt], 0, 0, 0);
            }
        }
        __syncthreads();
    }

    // ---- epilogue ----
#pragma unroll
    for (int jt = 0; jt < 2; ++jt) {
        const int gcol = jt * 16 + fr;
        float s = 0.f, q = 0.f;
        if (gcol < Nout) {
#pragma unroll
            for (int rg = 0; rg < 4; ++rg) {
                const float v = acc[jt][rg];
                C[(size_t)(bm + wm + quad * 4 + rg) * Nout + gcol] = v;
                s += v;
                q += v * v;
            }
        }
        s += __shfl_xor(s, 16); s += __shfl_xor(s, 32);
        q += __shfl_xor(q, 16); q += __shfl_xor(q, 32);
        if (quad == 0 && gcol < Nout) {
            atomicAdd(&s_out[gcol], s);
            atomicAdd(&q_out[gcol], q);
        }
    }
}

// ---------------------------------------------------------------------------
// x[M x 700] fp32 -> A1[M x 704] f16, zero-padded.
// ---------------------------------------------------------------------------
__global__ __launch_bounds__(256) void conv_x(const float* __restrict__ x,
                                              f16_t* __restrict__ A1) {
    const int idx = blockIdx.x * 256 + threadIdx.x;   // Mn * 88 groups of 8
    const int m = idx / 88, g = idx % 88;
    const int k8 = g * 8;
    const float* rp = x + (size_t)m * Jn + k8;
    float f[8];
    if (k8 + 8 <= Jn) {
        const float4 v0 = *(const float4*)rp;
        const float4 v1 = *(const float4*)(rp + 4);
        f[0] = v0.x; f[1] = v0.y; f[2] = v0.z; f[3] = v0.w;
        f[4] = v1.x; f[5] = v1.y; f[6] = v1.z; f[7] = v1.w;
    } else {
#pragma unroll
        for (int e = 0; e < 8; ++e) f[e] = (k8 + e < Jn) ? rp[e] : 0.f;
    }
    f16x8 hv;
#pragma unroll
    for (int e = 0; e < 8; ++e) hv[e] = (f16_t)f[e];
    *(f16x8*)&A1[(size_t)m * Jp + k8] = hv;
}

// ---------------------------------------------------------------------------
// Round-10: single merged weight-conversion kernel (was 3 launches).
// fp32 -> f16, zero-padded rows/cols; 8 elems/thread.
// ---------------------------------------------------------------------------
__global__ __launch_bounds__(256) void conv_w_all(const float* __restrict__ W1,
                                                  const float* __restrict__ W2,
                                                  const float* __restrict__ Wr,
                                                  f16_t* __restrict__ W1h,
                                                  f16_t* __restrict__ W2h,
                                                  f16_t* __restrict__ Wrh) {
    constexpr int n1 = Hn * (Jp / 8);      // 45056 groups
    constexpr int n2 = Hn * (Hn / 8);      // 32768
    constexpr int n3 = 128 * (Hn / 8);     // 8192
    int idx = blockIdx.x * 256 + threadIdx.x;
    const float* src; f16_t* dst; int N, K, KP;
    if (idx < n1)           { src = W1; dst = W1h; N = Hn;  K = Jn; KP = Jp; }
    else if (idx < n1 + n2) { src = W2; dst = W2h; N = Hn;  K = Hn; KP = Hn; idx -= n1; }
    else if (idx < n1 + n2 + n3) { src = Wr; dst = Wrh; N = On; K = Hn; KP = Hn; idx -= n1 + n2; }
    else return;
    const int n = idx / (KP / 8), g = idx % (KP / 8);
    const int k8 = g * 8;
    f16x8 hv;
#pragma unroll
    for (int e = 0; e < 8; ++e) {
        const float f = (n < N && k8 + e < K) ? src[(size_t)n * K + k8 + e] : 0.f;
        hv[e] = (f16_t)f;
    }
    *(f16x8*)&dst[(size_t)n * KP + k8] = hv;
}

// ---------------------------------------------------------------------------
// LIF scan, 2 channels/thread: BN-normalize (fp32 pre-acts) + sequential
// membrane update + spike. float2 reads, f16x2 writes (256 B/wave stores).
// Round-0 256-thr config (r7's 128-thr A/B was neutral -> keep measured-best).
// ---------------------------------------------------------------------------
__global__ __launch_bounds__(256) void lif_scan(const float* __restrict__ X,
                                                f16_t* __restrict__ S_out,
                                                const float* __restrict__ sums,
                                                const float* __restrict__ sumsq,
                                                const float* __restrict__ beta_raw,
                                                const float* __restrict__ gamma,
                                                const float* __restrict__ bias) {
    const int gid = blockIdx.x * 256 + threadIdx.x;   // Bn * Hn/2 = 32768
    const int b  = gid >> 8;
    const int cq = gid & 255;          // float2 index within row
    const int i0 = cq * 2;

    float g[2], bi[2], bt[2], ob[2];
#pragma unroll
    for (int e = 0; e < 2; ++e) {
        const int i = i0 + e;
        const float invM = 1.f / (float)Mn;
        const float mean = sums[i] * invM;
        const float var  = sumsq[i] * invM - mean * mean;
        const float inv  = rsqrtf(var + 1e-5f);
        g[e]  = gamma[i] * inv;
        bi[e] = bias[i] - mean * g[e];
        bt[e] = 1.f / (1.f + expf(-beta_raw[i]));
        ob[e] = 1.f - bt[e];
    }

    const float2* Xp = (const float2*)(X + (size_t)b * Tn * Hn) + cq;
    f16x2* Sp2 = (f16x2*)(S_out + (size_t)b * Tn * Hn) + cq;

    float U[2] = {0.f, 0.f}, Sp[2] = {0.f, 0.f};
#pragma unroll 8
    for (int t = 0; t < Tn; ++t) {
        const float2 v = Xp[(size_t)t * (Hn / 2)];
        const float vf[2] = {v.x, v.y};
        f16x2 so;
#pragma unroll
        for (int e = 0; e < 2; ++e) {
            const float xt = vf[e] * g[e] + bi[e];
            U[e] = bt[e] * (U[e] - Sp[e]) + ob[e] * xt;
            Sp[e] = (U[e] > 1.0f) ? 1.0f : 0.0f;
            so[e] = (f16_t)Sp[e];
        }
        Sp2[(size_t)t * (Hn / 2)] = so;
    }
}

// ---------------------------------------------------------------------------
// Readout: BN + linear EMA scan + softmax over 20 classes + sum over T.
// ---------------------------------------------------------------------------
__global__ __launch_bounds__(256) void readout_kernel(const float* __restrict__ A,
                                                      const float* __restrict__ sums,
                                                      const float* __restrict__ sumsq,
                                                      const float* __restrict__ beta_raw,
                                                      const float* __restrict__ gamma,
                                                      const float* __restrict__ bias,
                                                      float* __restrict__ out) {
    __shared__ float xs[Tn * On];
    __shared__ float gsh[On], bsh[On], betash[On];
    __shared__ float red[4][On];

    const int b = blockIdx.x;
    const int tid = threadIdx.x;

    if (tid < On) {
        const float invM = 1.f / (float)Mn;
        const float mean = sums[tid] * invM;
        const float var = sumsq[tid] * invM - mean * mean;
        const float inv = rsqrtf(var + 1e-5f);
        const float g = gamma[tid] * inv;
        gsh[tid] = g;
        bsh[tid] = bias[tid] - mean * g;
        betash[tid] = 1.f / (1.f + expf(-beta_raw[tid]));
    }
    __syncthreads();

    const float* Ab = A + (size_t)b * Tn * On;
    for (int idx = tid; idx < Tn * On; idx += 256) {
        const int o = idx % On;
        xs[idx] = Ab[idx] * gsh[o] + bsh[o];
    }
    __syncthreads();

    if (tid < On) {
        const float beta = betash[tid], omb = 1.f - beta;
        float U = 0.f;
        for (int t = 0; t < Tn; ++t) {
            U = beta * U + omb * xs[t * On + tid];
            xs[t * On + tid] = U;
        }
    }
    __syncthreads();

    float part[On];
#pragma unroll
    for (int o = 0; o < On; ++o) part[o] = 0.f;

    for (int t = tid; t < Tn; t += 256) {
        float v[On];
        float m = -1e30f;
#pragma unroll
        for (int o = 0; o < On; ++o) {
            v[o] = xs[t * On + o];
            m = fmaxf(m, v[o]);
        }
        float s = 0.f;
#pragma unroll
        for (int o = 0; o < On; ++o) {
            v[o] = expf(v[o] - m);
            s += v[o];
        }
        const float rs = 1.f / s;
#pragma unroll
        for (int o = 0; o < On; ++o) part[o] += v[o] * rs;
    }

#pragma unroll
    for (int o = 0; o < On; ++o) {
#pragma unroll
        for (int off = 32; off > 0; off >>= 1) part[o] += __shfl_down(part[o], off);
    }
    const int lane = tid & 63, wid = tid >> 6;
    if (lane == 0) {
#pragma unroll
        for (int o = 0; o < On; ++o) red[wid][o] = part[o];
    }
    __syncthreads();
    if (tid < On) out[b * On + tid] = red[0][tid] + red[1][tid] + red[2][tid] + red[3][tid];
}

// ---------------------------------------------------------------------------
extern "C" void kernel_launch(void* const* d_in, const int* in_sizes, int n_in,
                              void* d_out, int out_size, void* d_ws, size_t ws_size,
                              hipStream_t stream) {
    const float* x   = (const float*)d_in[0];
    const float* W1  = (const float*)d_in[1];
    const float* be1 = (const float*)d_in[2];
    const float* g1  = (const float*)d_in[3];
    const float* b1  = (const float*)d_in[4];
    const float* W2  = (const float*)d_in[5];
    const float* be2 = (const float*)d_in[6];
    const float* b2g = (const float*)d_in[7];
    const float* b2  = (const float*)d_in[8];
    const float* Wr  = (const float*)d_in[9];
    const float* ber = (const float*)d_in[10];
    const float* gr  = (const float*)d_in[11];
    const float* br  = (const float*)d_in[12];
    float* out = (float*)d_out;

    char* ws = (char*)d_ws;
    // Region 0: A1 (92 MB, dead after gemm1) overlapped with bufS (67 MB).
    const size_t r0Bytes   = (size_t)Mn * Jp * sizeof(f16_t);    // 92.3 MB
    const size_t bufCBytes = (size_t)Mn * Hn * sizeof(float);    // 134 MB fp32
    f16_t* A1   = (f16_t*)ws;
    f16_t* bufS = (f16_t*)ws;                  // overlaps A1 (sequenced)
    float* bufC = (float*)(ws + r0Bytes);
    char*  p    = ws + r0Bytes + bufCBytes;
    float* bufR = (float*)p;              p += (size_t)Mn * On * sizeof(float);
    f16_t* W1h  = (f16_t*)p;              p += (size_t)Hn * Jp * sizeof(f16_t);
    f16_t* W2h  = (f16_t*)p;              p += (size_t)Hn * Hn * sizeof(f16_t);
    f16_t* Wrh  = (f16_t*)p;              p += (size_t)128 * Hn * sizeof(f16_t);
    float* stats = (float*)p;
    float* s1 = stats;       float* q1 = s1 + Hn;
    float* s2 = q1 + Hn;     float* q2 = s2 + Hn;
    float* s3 = q2 + Hn;     float* q3 = s3 + 32;

    hipMemsetAsync(stats, 0, (4 * Hn + 64) * sizeof(float), stream);

    // f16 conversions (memory-bound; no conversion work inside GEMM K-loops).
    conv_x<<<(Mn * 88) / 256, 256, 0, stream>>>(x, A1);
    conv_w_all<<<(Hn * 88 + Hn * 64 + 128 * 64 + 255) / 256, 256, 0, stream>>>(
        W1, W2, Wr, W1h, W2h, Wrh);

    // Layer 1: A1[M x 704] * W1h[512 x 704]^T -> bufC fp32, fused s1/q1.
    gemm_f16<2, true><<<2 * (Mn / 128), 512, 0, stream>>>(A1, W1h, bufC, s1, q1,
        Jp, Jp, Jp / 64, Hn);
    lif_scan<<<(Bn * Hn / 2) / 256, 256, 0, stream>>>(bufC, bufS, s1, q1, be1, g1, b1);

    // Layer 2: spikes[M x 512] * W2h[512 x 512]^T -> bufC fp32, fused s2/q2.
    gemm_f16<2, true><<<2 * (Mn / 128), 512, 0, stream>>>(bufS, W2h, bufC, s2, q2,
        Hn, Hn, Hn / 64, Hn);
    lif_scan<<<(Bn * Hn / 2) / 256, 256, 0, stream>>>(bufC, bufS, s2, q2, be2, b2g, b2);

    // Readout (narrow-N): spikes[M x 512] * Wrh[32 x 512]^T -> bufR[M x 20].
    gemm_narrow<<<Mn / 128, 512, 0, stream>>>(bufS, Wrh, bufR, s3, q3,
        Hn, Hn, Hn / 64, On);
    readout_kernel<<<Bn, 256, 0, stream>>>(bufR, s3, q3, ber, gr, br, out);
}

// Round 5
// 524.063 us; speedup vs baseline: 1.1999x; 1.1999x over previous
//
#include <hip/hip_runtime.h>
#include <math.h>

typedef _Float16 f16_t;
typedef _Float16 f16x2 __attribute__((ext_vector_type(2)));
typedef _Float16 f16x8 __attribute__((ext_vector_type(8)));
typedef float f32x4 __attribute__((ext_vector_type(4)));

// Problem dims (fixed by setup_inputs)
constexpr int Bn = 128;       // batch
constexpr int Tn = 512;       // time steps
constexpr int Jn = 700;       // input features
constexpr int Jp = 704;       // padded to 64 multiple (11 x 64)
constexpr int Hn = 512;       // hidden
constexpr int On = 20;        // output classes
constexpr int Mn = Bn * Tn;   // 65536 rows

#define LDS_U32(p) ((__attribute__((address_space(3))) uint32_t*)(p))
#define GLB_U32(p) ((const __attribute__((address_space(1))) uint32_t*)(p))

// ---------------------------------------------------------------------------
// Round-0 GEMM structure (single-buffer, 2-barrier, gload_lds staging,
// 2 blocks/CU) -- all pipelining experiments (r8 dbuf, r9 fused-A) regressed.
//   C[M x Nout](fp32) = A[M x LDA](f16) * W[NP x LDW](f16)^T
// BK=64 per barrier, XOR bank swizzle on staging/fragments, 8 waves (2m x 4n).
//
// Round-11 change: EPILOGUE ATOMIC DECONTENTION. r4's counters showed
// gemm_narrow at 130us with 0.6% MfmaUtil / 1.1% VALUBusy -- pure atomic
// queueing: 8 waves x 512 blocks = 4096 atomicAdds per s/q address (only 20
// addresses). Fix: per-wave partials -> LDS (reusing dead sA tile; no LDS
// budget change) -> cross-wave reduce -> ONE atomicAdd per column per block.
// Contention 4096->512 (narrow), 1024->512 (wide). Pure re-association of
// adds feeding already-nondeterministic atomics.
// ---------------------------------------------------------------------------
template <int NT, bool SWZ>
__global__ __launch_bounds__(512, 4) void gemm_f16(
    const f16_t* __restrict__ A, const f16_t* __restrict__ W,
    float* __restrict__ C, float* __restrict__ s_out, float* __restrict__ q_out,
    int LDA, int LDW, int pairs, int Nout)
{
    constexpr int JT = 2 * NT;              // 16-col tiles per wave
    constexpr int NC = NT * 128;            // block N-tile cols
    __shared__ __align__(16) f16_t sA[2 * 4096];
    __shared__ __align__(16) f16_t sW[2 * NT * 4096];

    int bx, by;
    if (SWZ) {
        const int g = blockIdx.x;
        by = (g >> 4) * 8 + (g & 7);
        bx = (g >> 3) & 1;
    } else {
        bx = blockIdx.x;
        by = blockIdx.y;
    }
    const int tid  = threadIdx.x;
    const int bm   = by * 128;
    const int bn   = bx * NC;
    const int lane = tid & 63;
    const int wv   = tid >> 6;              // 0..7
    const int wm   = (wv & 1) * 64;
    const int wn   = (wv >> 1) * (NT * 32);
    const int fr   = lane & 15;
    const int quad = lane >> 4;
    const int srow = lane >> 2;                              // DMA row in chunk
    const int scol = (((lane & 3) ^ ((lane >> 3) & 3)) * 8); // swizzled fetch col
    const int ksw  = ((quad ^ ((fr >> 1) & 3)) * 8);         // swizzled frag col

    f32x4 acc[4][JT];
#pragma unroll
    for (int i = 0; i < 4; ++i)
#pragma unroll
        for (int j = 0; j < JT; ++j) acc[i][j] = {0.f, 0.f, 0.f, 0.f};

    for (int p = 0; p < pairs; ++p) {
        // ---- stage A: 2 k-slices x 8 chunks of 16 rows, spread over waves ----
#pragma unroll
        for (int cc = 0; cc < 2; ++cc) {
            const int c  = wv + cc * 8;     // 0..15
            const int s  = c >> 3;
            const int cr = (c & 7) * 16;
            const int kA = p * 64 + s * 32;
            const uint32_t off = __builtin_amdgcn_readfirstlane(s * 8192 + cr * 64);
            const f16_t* gp = A + (size_t)(bm + cr + srow) * LDA + kA + scol;
            __builtin_amdgcn_global_load_lds(GLB_U32(gp), LDS_U32((char*)sA + off), 16, 0, 0);
        }
        // ---- stage W: 2 k-slices x NT tiles x 8 chunks ----
#pragma unroll
        for (int cc = 0; cc < 2 * NT; ++cc) {
            const int c   = wv + cc * 8;
            const int h   = c / (NT * 8);
            const int rem = c % (NT * 8);
            const int nt  = rem >> 3;
            const int cr  = (rem & 7) * 16;
            const int kW  = p * 64 + h * 32;
            const uint32_t off = __builtin_amdgcn_readfirstlane((h * NT + nt) * 8192 + cr * 64);
            const f16_t* gp = W + (size_t)(bn + nt * 128 + cr + srow) * LDW + kW + scol;
            __builtin_amdgcn_global_load_lds(GLB_U32(gp), LDS_U32((char*)sW + off), 16, 0, 0);
        }
        __syncthreads();

        // ---- consume: 2 x (4 x JT) MFMA per wave between barriers ----
#pragma unroll
        for (int h = 0; h < 2; ++h) {
            f16x8 av[4];
#pragma unroll
            for (int i = 0; i < 4; ++i)
                av[i] = *(const f16x8*)&sA[h * 4096 + (wm + i * 16 + fr) * 32 + ksw];
            f16x8 wf[JT];
#pragma unroll
            for (int jt = 0; jt < JT; ++jt) {
                const int n = wn + jt * 16 + fr;
                wf[jt] = *(const f16x8*)&sW[(h * NT + (n >> 7)) * 4096 + (n & 127) * 32 + ksw];
            }
#pragma unroll
            for (int i = 0; i < 4; ++i)
#pragma unroll
                for (int jt = 0; jt < JT; ++jt)
                    acc[i][jt] = __builtin_amdgcn_mfma_f32_16x16x32_f16(av[i], wf[jt], acc[i][jt], 0, 0, 0);
        }
        __syncthreads();
    }

    // ---- epilogue: fp32 store + block-reduced BN stats (LDS reuse of sA) ----
    // After the final K-loop barrier, sA/sW are dead -> reuse as scratch.
    float* redS = (float*)sA;               // [2][NC]
    float* redQ = redS + 2 * NC;            // [2][NC]  (4*NC floats <= 4 KB)
#pragma unroll
    for (int jt = 0; jt < JT; ++jt) {
        const int gcol = bn + wn + jt * 16 + fr;
        float s = 0.f, q = 0.f;
        if (gcol < Nout) {
#pragma unroll
            for (int i = 0; i < 4; ++i) {
#pragma unroll
                for (int rg = 0; rg < 4; ++rg) {
                    const float v = acc[i][jt][rg];
                    C[(size_t)(bm + wm + i * 16 + quad * 4 + rg) * Nout + gcol] = v;
                    s += v;
                    q += v * v;
                }
            }
        }
        s += __shfl_xor(s, 16); s += __shfl_xor(s, 32);
        q += __shfl_xor(q, 16); q += __shfl_xor(q, 32);
        if (quad == 0) {
            const int lc = wn + jt * 16 + fr;          // 0..NC-1
            redS[(wv & 1) * NC + lc] = s;
            redQ[(wv & 1) * NC + lc] = q;
        }
    }
    __syncthreads();
    if (tid < NC) {
        const int gcol = bn + tid;
        if (gcol < Nout) {
            atomicAdd(&s_out[gcol], redS[tid] + redS[NC + tid]);
            atomicAdd(&q_out[gcol], redQ[tid] + redQ[NC + tid]);
        }
    }
}

// ---------------------------------------------------------------------------
// Narrow-N GEMM for the readout layer: 8 waves split 8x1 over M (wave =
// 16 rows x 32 cols), W-tile 32 rows (4 KB LDS), 4 MFMA/iter/wave. Same MFMA
// shape / K-order / staging swizzle as wide -> bufR bit-identical.
// Round-11: block-reduced stats epilogue (see header above) -- this kernel
// was 130us of pure atomic queueing (4096 contenders on 20 addresses).
// ---------------------------------------------------------------------------
__global__ __launch_bounds__(512, 4) void gemm_narrow(
    const f16_t* __restrict__ A, const f16_t* __restrict__ W,
    float* __restrict__ C, float* __restrict__ s_out, float* __restrict__ q_out,
    int LDA, int LDW, int pairs, int Nout)
{
    __shared__ __align__(16) f16_t sA[2 * 4096];   // 2 slices x 128 rows x 32
    __shared__ __align__(16) f16_t sW[2 * 1024];   // 2 slices x  32 rows x 32

    const int tid  = threadIdx.x;
    const int bm   = blockIdx.x * 128;
    const int lane = tid & 63;
    const int wv   = tid >> 6;              // 0..7
    const int wm   = wv * 16;               // 8 waves x 16 rows = 128
    const int fr   = lane & 15;
    const int quad = lane >> 4;
    const int srow = lane >> 2;
    const int scol = (((lane & 3) ^ ((lane >> 3) & 3)) * 8);
    const int ksw  = ((quad ^ ((fr >> 1) & 3)) * 8);

    f32x4 acc[2];
    acc[0] = {0.f, 0.f, 0.f, 0.f};
    acc[1] = {0.f, 0.f, 0.f, 0.f};

    for (int p = 0; p < pairs; ++p) {
        // ---- stage A: identical to wide path ----
#pragma unroll
        for (int cc = 0; cc < 2; ++cc) {
            const int c  = wv + cc * 8;
            const int s  = c >> 3;
            const int cr = (c & 7) * 16;
            const int kA = p * 64 + s * 32;
            const uint32_t off = __builtin_amdgcn_readfirstlane(s * 8192 + cr * 64);
            const f16_t* gp = A + (size_t)(bm + cr + srow) * LDA + kA + scol;
            __builtin_amdgcn_global_load_lds(GLB_U32(gp), LDS_U32((char*)sA + off), 16, 0, 0);
        }
        // ---- stage W: 2 slices x 2 chunks of 16 rows = 4 chunks, waves 0-3 ----
        if (wv < 4) {
            const int s  = wv >> 1;
            const int cr = (wv & 1) * 16;
            const int kW = p * 64 + s * 32;
            const uint32_t off = __builtin_amdgcn_readfirstlane(s * 2048 + cr * 64);
            const f16_t* gp = W + (size_t)(cr + srow) * LDW + kW + scol;
            __builtin_amdgcn_global_load_lds(GLB_U32(gp), LDS_U32((char*)sW + off), 16, 0, 0);
        }
        __syncthreads();

#pragma unroll
        for (int h = 0; h < 2; ++h) {
            const f16x8 av = *(const f16x8*)&sA[h * 4096 + (wm + fr) * 32 + ksw];
#pragma unroll
            for (int jt = 0; jt < 2; ++jt) {
                const f16x8 wf = *(const f16x8*)&sW[h * 1024 + (jt * 16 + fr) * 32 + ksw];
                acc[jt] = __builtin_amdgcn_mfma_f32_16x16x32_f16(av, wf, acc[jt], 0, 0, 0);
            }
        }
        __syncthreads();
    }

    // ---- epilogue: store + block-reduced stats (one atomic/col/block) ----
    float* redS = (float*)sA;               // [8][32]
    float* redQ = redS + 256;               // [8][32]
#pragma unroll
    for (int jt = 0; jt < 2; ++jt) {
        const int gcol = jt * 16 + fr;
        float s = 0.f, q = 0.f;
        if (gcol < Nout) {
#pragma unroll
            for (int rg = 0; rg < 4; ++rg) {
                const float v = acc[jt][rg];
                C[(size_t)(bm + wm + quad * 4 + rg) * Nout + gcol] = v;
                s += v;
                q += v * v;
            }
        }
        s += __shfl_xor(s, 16); s += __shfl_xor(s, 32);
        q += __shfl_xor(q, 16); q += __shfl_xor(q, 32);
        if (quad == 0) {
            redS[wv * 32 + gcol] = s;
            redQ[wv * 32 + gcol] = q;
        }
    }
    __syncthreads();
    if (tid < 32) {
        float ss = 0.f, qq = 0.f;
#pragma unroll
        for (int w = 0; w < 8; ++w) {
            ss += redS[w * 32 + tid];
            qq += redQ[w * 32 + tid];
        }
        if (tid < Nout) {
            atomicAdd(&s_out[tid], ss);
            atomicAdd(&q_out[tid], qq);
        }
    }
}

// ---------------------------------------------------------------------------
// x[M x 700] fp32 -> A1[M x 704] f16, zero-padded.
// ---------------------------------------------------------------------------
__global__ __launch_bounds__(256) void conv_x(const float* __restrict__ x,
                                              f16_t* __restrict__ A1) {
    const int idx = blockIdx.x * 256 + threadIdx.x;   // Mn * 88 groups of 8
    const int m = idx / 88, g = idx % 88;
    const int k8 = g * 8;
    const float* rp = x + (size_t)m * Jn + k8;
    float f[8];
    if (k8 + 8 <= Jn) {
        const float4 v0 = *(const float4*)rp;
        const float4 v1 = *(const float4*)(rp + 4);
        f[0] = v0.x; f[1] = v0.y; f[2] = v0.z; f[3] = v0.w;
        f[4] = v1.x; f[5] = v1.y; f[6] = v1.z; f[7] = v1.w;
    } else {
#pragma unroll
        for (int e = 0; e < 8; ++e) f[e] = (k8 + e < Jn) ? rp[e] : 0.f;
    }
    f16x8 hv;
#pragma unroll
    for (int e = 0; e < 8; ++e) hv[e] = (f16_t)f[e];
    *(f16x8*)&A1[(size_t)m * Jp + k8] = hv;
}

// ---------------------------------------------------------------------------
// Single merged weight-conversion kernel. fp32 -> f16, zero-padded; 8/thread.
// ---------------------------------------------------------------------------
__global__ __launch_bounds__(256) void conv_w_all(const float* __restrict__ W1,
                                                  const float* __restrict__ W2,
                                                  const float* __restrict__ Wr,
                                                  f16_t* __restrict__ W1h,
                                                  f16_t* __restrict__ W2h,
                                                  f16_t* __restrict__ Wrh) {
    constexpr int n1 = Hn * (Jp / 8);      // 45056 groups
    constexpr int n2 = Hn * (Hn / 8);      // 32768
    constexpr int n3 = 128 * (Hn / 8);     // 8192
    int idx = blockIdx.x * 256 + threadIdx.x;
    const float* src; f16_t* dst; int N, K, KP;
    if (idx < n1)           { src = W1; dst = W1h; N = Hn;  K = Jn; KP = Jp; }
    else if (idx < n1 + n2) { src = W2; dst = W2h; N = Hn;  K = Hn; KP = Hn; idx -= n1; }
    else if (idx < n1 + n2 + n3) { src = Wr; dst = Wrh; N = On; K = Hn; KP = Hn; idx -= n1 + n2; }
    else return;
    const int n = idx / (KP / 8), g = idx % (KP / 8);
    const int k8 = g * 8;
    f16x8 hv;
#pragma unroll
    for (int e = 0; e < 8; ++e) {
        const float f = (n < N && k8 + e < K) ? src[(size_t)n * K + k8 + e] : 0.f;
        hv[e] = (f16_t)f;
    }
    *(f16x8*)&dst[(size_t)n * KP + k8] = hv;
}

// ---------------------------------------------------------------------------
// LIF scan, 2 channels/thread: BN-normalize (fp32 pre-acts) + sequential
// membrane update + spike. float2 reads, f16x2 writes (256 B/wave stores).
// ---------------------------------------------------------------------------
__global__ __launch_bounds__(256) void lif_scan(const float* __restrict__ X,
                                                f16_t* __restrict__ S_out,
                                                const float* __restrict__ sums,
                                                const float* __restrict__ sumsq,
                                                const float* __restrict__ beta_raw,
                                                const float* __restrict__ gamma,
                                                const float* __restrict__ bias) {
    const int gid = blockIdx.x * 256 + threadIdx.x;   // Bn * Hn/2 = 32768
    const int b  = gid >> 8;
    const int cq = gid & 255;          // float2 index within row
    const int i0 = cq * 2;

    float g[2], bi[2], bt[2], ob[2];
#pragma unroll
    for (int e = 0; e < 2; ++e) {
        const int i = i0 + e;
        const float invM = 1.f / (float)Mn;
        const float mean = sums[i] * invM;
        const float var  = sumsq[i] * invM - mean * mean;
        const float inv  = rsqrtf(var + 1e-5f);
        g[e]  = gamma[i] * inv;
        bi[e] = bias[i] - mean * g[e];
        bt[e] = 1.f / (1.f + expf(-beta_raw[i]));
        ob[e] = 1.f - bt[e];
    }

    const float2* Xp = (const float2*)(X + (size_t)b * Tn * Hn) + cq;
    f16x2* Sp2 = (f16x2*)(S_out + (size_t)b * Tn * Hn) + cq;

    float U[2] = {0.f, 0.f}, Sp[2] = {0.f, 0.f};
#pragma unroll 8
    for (int t = 0; t < Tn; ++t) {
        const float2 v = Xp[(size_t)t * (Hn / 2)];
        const float vf[2] = {v.x, v.y};
        f16x2 so;
#pragma unroll
        for (int e = 0; e < 2; ++e) {
            const float xt = vf[e] * g[e] + bi[e];
            U[e] = bt[e] * (U[e] - Sp[e]) + ob[e] * xt;
            Sp[e] = (U[e] > 1.0f) ? 1.0f : 0.0f;
            so[e] = (f16_t)Sp[e];
        }
        Sp2[(size_t)t * (Hn / 2)] = so;
    }
}

// ---------------------------------------------------------------------------
// Readout: BN + linear EMA scan + softmax over 20 classes + sum over T.
// ---------------------------------------------------------------------------
__global__ __launch_bounds__(256) void readout_kernel(const float* __restrict__ A,
                                                      const float* __restrict__ sums,
                                                      const float* __restrict__ sumsq,
                                                      const float* __restrict__ beta_raw,
                                                      const float* __restrict__ gamma,
                                                      const float* __restrict__ bias,
                                                      float* __restrict__ out) {
    __shared__ float xs[Tn * On];
    __shared__ float gsh[On], bsh[On], betash[On];
    __shared__ float red[4][On];

    const int b = blockIdx.x;
    const int tid = threadIdx.x;

    if (tid < On) {
        const float invM = 1.f / (float)Mn;
        const float mean = sums[tid] * invM;
        const float var = sumsq[tid] * invM - mean * mean;
        const float inv = rsqrtf(var + 1e-5f);
        const float g = gamma[tid] * inv;
        gsh[tid] = g;
        bsh[tid] = bias[tid] - mean * g;
        betash[tid] = 1.f / (1.f + expf(-beta_raw[tid]));
    }
    __syncthreads();

    const float* Ab = A + (size_t)b * Tn * On;
    for (int idx = tid; idx < Tn * On; idx += 256) {
        const int o = idx % On;
        xs[idx] = Ab[idx] * gsh[o] + bsh[o];
    }
    __syncthreads();

    if (tid < On) {
        const float beta = betash[tid], omb = 1.f - beta;
        float U = 0.f;
        for (int t = 0; t < Tn; ++t) {
            U = beta * U + omb * xs[t * On + tid];
            xs[t * On + tid] = U;
        }
    }
    __syncthreads();

    float part[On];
#pragma unroll
    for (int o = 0; o < On; ++o) part[o] = 0.f;

    for (int t = tid; t < Tn; t += 256) {
        float v[On];
        float m = -1e30f;
#pragma unroll
        for (int o = 0; o < On; ++o) {
            v[o] = xs[t * On + o];
            m = fmaxf(m, v[o]);
        }
        float s = 0.f;
#pragma unroll
        for (int o = 0; o < On; ++o) {
            v[o] = expf(v[o] - m);
            s += v[o];
        }
        const float rs = 1.f / s;
#pragma unroll
        for (int o = 0; o < On; ++o) part[o] += v[o] * rs;
    }

#pragma unroll
    for (int o = 0; o < On; ++o) {
#pragma unroll
        for (int off = 32; off > 0; off >>= 1) part[o] += __shfl_down(part[o], off);
    }
    const int lane = tid & 63, wid = tid >> 6;
    if (lane == 0) {
#pragma unroll
        for (int o = 0; o < On; ++o) red[wid][o] = part[o];
    }
    __syncthreads();
    if (tid < On) out[b * On + tid] = red[0][tid] + red[1][tid] + red[2][tid] + red[3][tid];
}

// ---------------------------------------------------------------------------
extern "C" void kernel_launch(void* const* d_in, const int* in_sizes, int n_in,
                              void* d_out, int out_size, void* d_ws, size_t ws_size,
                              hipStream_t stream) {
    const float* x   = (const float*)d_in[0];
    const float* W1  = (const float*)d_in[1];
    const float* be1 = (const float*)d_in[2];
    const float* g1  = (const float*)d_in[3];
    const float* b1  = (const float*)d_in[4];
    const float* W2  = (const float*)d_in[5];
    const float* be2 = (const float*)d_in[6];
    const float* b2g = (const float*)d_in[7];
    const float* b2  = (const float*)d_in[8];
    const float* Wr  = (const float*)d_in[9];
    const float* ber = (const float*)d_in[10];
    const float* gr  = (const float*)d_in[11];
    const float* br  = (const float*)d_in[12];
    float* out = (float*)d_out;

    char* ws = (char*)d_ws;
    // Region 0: A1 (92 MB, dead after gemm1) overlapped with bufS (67 MB).
    const size_t r0Bytes   = (size_t)Mn * Jp * sizeof(f16_t);    // 92.3 MB
    const size_t bufCBytes = (size_t)Mn * Hn * sizeof(float);    // 134 MB fp32
    f16_t* A1   = (f16_t*)ws;
    f16_t* bufS = (f16_t*)ws;                  // overlaps A1 (sequenced)
    float* bufC = (float*)(ws + r0Bytes);
    char*  p    = ws + r0Bytes + bufCBytes;
    float* bufR = (float*)p;              p += (size_t)Mn * On * sizeof(float);
    f16_t* W1h  = (f16_t*)p;              p += (size_t)Hn * Jp * sizeof(f16_t);
    f16_t* W2h  = (f16_t*)p;              p += (size_t)Hn * Hn * sizeof(f16_t);
    f16_t* Wrh  = (f16_t*)p;              p += (size_t)128 * Hn * sizeof(f16_t);
    float* stats = (float*)p;
    float* s1 = stats;       float* q1 = s1 + Hn;
    float* s2 = q1 + Hn;     float* q2 = s2 + Hn;
    float* s3 = q2 + Hn;     float* q3 = s3 + 32;

    hipMemsetAsync(stats, 0, (4 * Hn + 64) * sizeof(float), stream);

    // f16 conversions (memory-bound; no conversion work inside GEMM K-loops).
    conv_x<<<(Mn * 88) / 256, 256, 0, stream>>>(x, A1);
    conv_w_all<<<(Hn * 88 + Hn * 64 + 128 * 64 + 255) / 256, 256, 0, stream>>>(
        W1, W2, Wr, W1h, W2h, Wrh);

    // Layer 1: A1[M x 704] * W1h[512 x 704]^T -> bufC fp32, fused s1/q1.
    gemm_f16<2, true><<<2 * (Mn / 128), 512, 0, stream>>>(A1, W1h, bufC, s1, q1,
        Jp, Jp, Jp / 64, Hn);
    lif_scan<<<(Bn * Hn / 2) / 256, 256, 0, stream>>>(bufC, bufS, s1, q1, be1, g1, b1);

    // Layer 2: spikes[M x 512] * W2h[512 x 512]^T -> bufC fp32, fused s2/q2.
    gemm_f16<2, true><<<2 * (Mn / 128), 512, 0, stream>>>(bufS, W2h, bufC, s2, q2,
        Hn, Hn, Hn / 64, Hn);
    lif_scan<<<(Bn * Hn / 2) / 256, 256, 0, stream>>>(bufC, bufS, s2, q2, be2, b2g, b2);

    // Readout (narrow-N): spikes[M x 512] * Wrh[32 x 512]^T -> bufR[M x 20].
    gemm_narrow<<<Mn / 128, 512, 0, stream>>>(bufS, Wrh, bufR, s3, q3,
        Hn, Hn, Hn / 64, On);
    readout_kernel<<<Bn, 256, 0, stream>>>(bufR, s3, q3, ber, gr, br, out);
}